// Round 1
// baseline (349.940 us; speedup 1.0000x reference)
//
#include <hip/hip_runtime.h>

#define T_SEQ 2048
#define C_DIM 1024
#define HD 64

typedef __attribute__((ext_vector_type(8))) short short8;
typedef __attribute__((ext_vector_type(4))) float f32x4;

__device__ __forceinline__ unsigned short f2bf(float f) {
  unsigned int u = __builtin_bit_cast(unsigned int, f);
  u += 0x7fffu + ((u >> 16) & 1u);
  return (unsigned short)(u >> 16);
}

// dst[n][k] = src[k][col_off + n], converted to bf16. dims 1024x1024.
__global__ __launch_bounds__(256) void transpose_w(
    const float* __restrict__ src, unsigned short* __restrict__ dst,
    int src_ld, int col_off) {
  int n = blockIdx.x * 16 + threadIdx.x;
  int k = blockIdx.y * 16 + threadIdx.y;
  dst[(size_t)n * C_DIM + k] = f2bf(src[(size_t)k * src_ld + col_off + n]);
}

// ---------------- GEMM1: K[8192][1024] (bf16) = x(f32) @ Wkt^T + bias ----
// A: f32 [M][1024]; Bt: bf16 [N][K] row-major (pre-transposed weight)
__global__ __launch_bounds__(256) void gemm_xw(
    const float* __restrict__ A, const unsigned short* __restrict__ Bt,
    const float* __restrict__ bias, unsigned short* __restrict__ out) {
  __shared__ unsigned short Als[128][40];
  __shared__ unsigned short Bls[128][40];
  const int tid = threadIdx.x;
  const int l = tid & 63, w = tid >> 6;
  const int wr = w >> 1, wc = w & 1;
  const int rb = blockIdx.x * 128, cb = blockIdx.y * 128;
  const int srow = tid >> 1, sh = (tid & 1) * 16;
  f32x4 acc[4][4] = {};
  for (int kb = 0; kb < 1024; kb += 32) {
    const f32x4* ap = (const f32x4*)(A + (size_t)(rb + srow) * 1024 + kb + sh);
    f32x4 a0 = ap[0], a1 = ap[1], a2 = ap[2], a3 = ap[3];
    short8 s0, s1;
#pragma unroll
    for (int i = 0; i < 4; ++i) {
      s0[i]     = (short)f2bf(a0[i]);
      s0[i + 4] = (short)f2bf(a1[i]);
      s1[i]     = (short)f2bf(a2[i]);
      s1[i + 4] = (short)f2bf(a3[i]);
    }
    *(short8*)&Als[srow][sh] = s0;
    *(short8*)&Als[srow][sh + 8] = s1;
    const short8* bp = (const short8*)(Bt + (size_t)(cb + srow) * 1024 + kb + sh);
    short8 b0 = bp[0], b1 = bp[1];
    *(short8*)&Bls[srow][sh] = b0;
    *(short8*)&Bls[srow][sh + 8] = b1;
    __syncthreads();
    short8 af[4], bfr[4];
#pragma unroll
    for (int m = 0; m < 4; ++m)
      af[m] = *(const short8*)&Als[wr * 64 + m * 16 + (l & 15)][(l >> 4) * 8];
#pragma unroll
    for (int n = 0; n < 4; ++n)
      bfr[n] = *(const short8*)&Bls[wc * 64 + n * 16 + (l & 15)][(l >> 4) * 8];
#pragma unroll
    for (int m = 0; m < 4; ++m)
#pragma unroll
      for (int n = 0; n < 4; ++n)
        acc[m][n] = __builtin_amdgcn_mfma_f32_16x16x32_bf16(af[m], bfr[n], acc[m][n], 0, 0, 0);
    __syncthreads();
  }
  const int rg = (l >> 4) * 4, cg = l & 15;
#pragma unroll
  for (int m = 0; m < 4; ++m)
#pragma unroll
    for (int n = 0; n < 4; ++n) {
      int col = cb + wc * 64 + n * 16 + cg;
      float bv = bias[col];
#pragma unroll
      for (int r = 0; r < 4; ++r) {
        int row = rb + wr * 64 + m * 16 + rg + r;
        out[(size_t)row * 1024 + col] = f2bf(acc[m][n][r] + bv);
      }
    }
}

// ---------------- GEMM2: out[8192][1024] (f32) = y(bf16) @ Wpt^T + bias --
__global__ __launch_bounds__(256) void gemm_yw(
    const unsigned short* __restrict__ A, const unsigned short* __restrict__ Bt,
    const float* __restrict__ bias, float* __restrict__ out) {
  __shared__ unsigned short Als[128][40];
  __shared__ unsigned short Bls[128][40];
  const int tid = threadIdx.x;
  const int l = tid & 63, w = tid >> 6;
  const int wr = w >> 1, wc = w & 1;
  const int rb = blockIdx.x * 128, cb = blockIdx.y * 128;
  const int srow = tid >> 1, sh = (tid & 1) * 16;
  f32x4 acc[4][4] = {};
  for (int kb = 0; kb < 1024; kb += 32) {
    const short8* ap = (const short8*)(A + (size_t)(rb + srow) * 1024 + kb + sh);
    short8 a0 = ap[0], a1 = ap[1];
    *(short8*)&Als[srow][sh] = a0;
    *(short8*)&Als[srow][sh + 8] = a1;
    const short8* bp = (const short8*)(Bt + (size_t)(cb + srow) * 1024 + kb + sh);
    short8 b0 = bp[0], b1 = bp[1];
    *(short8*)&Bls[srow][sh] = b0;
    *(short8*)&Bls[srow][sh + 8] = b1;
    __syncthreads();
    short8 af[4], bfr[4];
#pragma unroll
    for (int m = 0; m < 4; ++m)
      af[m] = *(const short8*)&Als[wr * 64 + m * 16 + (l & 15)][(l >> 4) * 8];
#pragma unroll
    for (int n = 0; n < 4; ++n)
      bfr[n] = *(const short8*)&Bls[wc * 64 + n * 16 + (l & 15)][(l >> 4) * 8];
#pragma unroll
    for (int m = 0; m < 4; ++m)
#pragma unroll
      for (int n = 0; n < 4; ++n)
        acc[m][n] = __builtin_amdgcn_mfma_f32_16x16x32_bf16(af[m], bfr[n], acc[m][n], 0, 0, 0);
    __syncthreads();
  }
  const int rg = (l >> 4) * 4, cg = l & 15;
#pragma unroll
  for (int m = 0; m < 4; ++m)
#pragma unroll
    for (int n = 0; n < 4; ++n) {
      int col = cb + wc * 64 + n * 16 + cg;
      float bv = bias[col];
#pragma unroll
      for (int r = 0; r < 4; ++r) {
        int row = rb + wr * 64 + m * 16 + rg + r;
        out[(size_t)row * 1024 + col] = acc[m][n][r] + bv;
      }
    }
}

// ---------------- Flash attention: Q=K=V=Kmat head slices -----------------
// block = 4 waves x 16 q-rows = 64 q rows; grid = B*H*(T/64) = 2048
__global__ __launch_bounds__(256) void attn_fwd(
    const unsigned short* __restrict__ Kmat, unsigned short* __restrict__ Y) {
  const int qt = blockIdx.x & 31;
  const int bh = blockIdx.x >> 5;
  const int b = bh >> 4, h = bh & 15;
  const int tid = threadIdx.x, w = tid >> 6, l = tid & 63;
  const unsigned short* base = Kmat + (size_t)b * T_SEQ * C_DIM + h * HD;

  __shared__ unsigned short Kls[64][72];
  __shared__ unsigned short Vtls[64][72];   // Vt[d][k]
  __shared__ unsigned short Pls[4][16][72]; // per-wave P

  const int q0 = qt * 64 + w * 16;
  const int rg = (l >> 4) * 4, cg = l & 15;

  // Q fragments (row = q0 + (l&15), k = c*32 + (l>>4)*8 + j)
  short8 qf0, qf1;
  {
    const unsigned short* qp = base + (size_t)(q0 + (l & 15)) * C_DIM + ((l >> 4) * 8);
    qf0 = *(const short8*)qp;
    qf1 = *(const short8*)(qp + 32);
  }

  f32x4 yacc[4] = {};
  float mrun[4], lrun[4];
#pragma unroll
  for (int r = 0; r < 4; ++r) { mrun[r] = -INFINITY; lrun[r] = 0.f; }

  const int skk = tid >> 2;          // 0..63 kv row
  const int sd0 = (tid & 3) * 16;    // d offset

  for (int kv = 0; kv <= qt; ++kv) {
    const int kvb = kv * 64;
    // stage K row-major and V transposed
    const unsigned short* src = base + (size_t)(kvb + skk) * C_DIM + sd0;
    short8 v0 = *(const short8*)src;
    short8 v1 = *(const short8*)(src + 8);
    *(short8*)&Kls[skk][sd0] = v0;
    *(short8*)&Kls[skk][sd0 + 8] = v1;
#pragma unroll
    for (int e = 0; e < 8; ++e) Vtls[sd0 + e][skk] = (unsigned short)v0[e];
#pragma unroll
    for (int e = 0; e < 8; ++e) Vtls[sd0 + 8 + e][skk] = (unsigned short)v1[e];
    __syncthreads();

    // S = Q K^T  (per-wave 16x64, 4 n-tiles)
    f32x4 s[4];
#pragma unroll
    for (int n = 0; n < 4; ++n) {
      short8 kf0 = *(const short8*)&Kls[n * 16 + (l & 15)][(l >> 4) * 8];
      short8 kf1 = *(const short8*)&Kls[n * 16 + (l & 15)][32 + (l >> 4) * 8];
      f32x4 acc = {};
      acc = __builtin_amdgcn_mfma_f32_16x16x32_bf16(qf0, kf0, acc, 0, 0, 0);
      acc = __builtin_amdgcn_mfma_f32_16x16x32_bf16(qf1, kf1, acc, 0, 0, 0);
      s[n] = acc;
    }

    const bool diag = (kv == qt);
#pragma unroll
    for (int n = 0; n < 4; ++n)
#pragma unroll
      for (int r = 0; r < 4; ++r) {
        float v = s[n][r] * 0.125f;
        if (diag && (kvb + n * 16 + cg) > (q0 + rg + r)) v = -INFINITY;
        s[n][r] = v;
      }

    // online softmax: row r lives across the 16 lanes sharing (l>>4)
    float mt[4];
#pragma unroll
    for (int r = 0; r < 4; ++r)
      mt[r] = fmaxf(fmaxf(s[0][r], s[1][r]), fmaxf(s[2][r], s[3][r]));
#pragma unroll
    for (int msk = 1; msk <= 8; msk <<= 1)
#pragma unroll
      for (int r = 0; r < 4; ++r)
        mt[r] = fmaxf(mt[r], __shfl_xor(mt[r], msk, 64));

    float alpha[4], psum[4];
#pragma unroll
    for (int r = 0; r < 4; ++r) {
      float mn = fmaxf(mrun[r], mt[r]);
      alpha[r] = __expf(mrun[r] - mn);
      mrun[r] = mn;
      psum[r] = 0.f;
    }
#pragma unroll
    for (int n = 0; n < 4; ++n)
#pragma unroll
      for (int r = 0; r < 4; ++r) {
        float p = __expf(s[n][r] - mrun[r]);
        s[n][r] = p;
        psum[r] += p;
      }
#pragma unroll
    for (int msk = 1; msk <= 8; msk <<= 1)
#pragma unroll
      for (int r = 0; r < 4; ++r)
        psum[r] += __shfl_xor(psum[r], msk, 64);
#pragma unroll
    for (int r = 0; r < 4; ++r)
      lrun[r] = lrun[r] * alpha[r] + psum[r];
#pragma unroll
    for (int dt = 0; dt < 4; ++dt)
#pragma unroll
      for (int r = 0; r < 4; ++r)
        yacc[dt][r] *= alpha[r];

    // P (C/D layout) -> LDS row-major for A-fragment reads
#pragma unroll
    for (int n = 0; n < 4; ++n)
#pragma unroll
      for (int r = 0; r < 4; ++r)
        Pls[w][rg + r][n * 16 + cg] = f2bf(s[n][r]);

    __syncthreads();

    // y += P @ V  (4 d-tiles x 2 k-chunks)
#pragma unroll
    for (int dt = 0; dt < 4; ++dt) {
#pragma unroll
      for (int c = 0; c < 2; ++c) {
        short8 pf = *(const short8*)&Pls[w][l & 15][c * 32 + (l >> 4) * 8];
        short8 vf = *(const short8*)&Vtls[dt * 16 + (l & 15)][c * 32 + (l >> 4) * 8];
        yacc[dt] = __builtin_amdgcn_mfma_f32_16x16x32_bf16(pf, vf, yacc[dt], 0, 0, 0);
      }
    }
    __syncthreads();
  }

#pragma unroll
  for (int dt = 0; dt < 4; ++dt)
#pragma unroll
    for (int r = 0; r < 4; ++r) {
      int row = q0 + rg + r;
      int col = h * HD + dt * 16 + cg;
      Y[(size_t)(b * T_SEQ + row) * C_DIM + col] = f2bf(yacc[dt][r] / lrun[r]);
    }
}

extern "C" void kernel_launch(void* const* d_in, const int* in_sizes, int n_in,
                              void* d_out, int out_size, void* d_ws, size_t ws_size,
                              hipStream_t stream) {
  const float* x      = (const float*)d_in[0];
  const float* W_attn = (const float*)d_in[1];
  const float* b_attn = (const float*)d_in[2];
  const float* W_proj = (const float*)d_in[3];
  const float* b_proj = (const float*)d_in[4];
  float* out = (float*)d_out;

  unsigned short* Wkt  = (unsigned short*)d_ws;                 // 1024x1024 bf16
  unsigned short* Wpt  = Wkt + (size_t)1024 * 1024;             // 1024x1024 bf16
  unsigned short* Kbuf = Wpt + (size_t)1024 * 1024;             // 8192x1024 bf16
  unsigned short* Ybuf = Kbuf + (size_t)8192 * 1024;            // 8192x1024 bf16

  // Wkt[n][k] = W_attn[k][1024+n]; Wpt[n][k] = W_proj[k][n]
  transpose_w<<<dim3(64, 64), dim3(16, 16), 0, stream>>>(W_attn, Wkt, 3072, 1024);
  transpose_w<<<dim3(64, 64), dim3(16, 16), 0, stream>>>(W_proj, Wpt, 1024, 0);

  // K = x @ Wk + b_attn[C:2C]  (bf16 out)
  gemm_xw<<<dim3(64, 8), 256, 0, stream>>>(x, Wkt, b_attn + 1024, Kbuf);

  // y = causal_attn(K,K,K)  (bf16 out)
  attn_fwd<<<dim3(2048), 256, 0, stream>>>(Kbuf, Ybuf);

  // out = y @ Wp + b_proj  (f32 out)
  gemm_yw<<<dim3(64, 8), 256, 0, stream>>>(Ybuf, Wpt, b_proj, out);
}

// Round 3
// 331.667 us; speedup vs baseline: 1.0551x; 1.0551x over previous
//
#include <hip/hip_runtime.h>

#define T_SEQ 2048
#define C_DIM 1024
#define HD 64

typedef __attribute__((ext_vector_type(8))) short short8;
typedef __attribute__((ext_vector_type(4))) float f32x4;
typedef __attribute__((ext_vector_type(4))) unsigned int uint4v;

__device__ __forceinline__ unsigned short f2bf(float f) {
  unsigned int u = __builtin_bit_cast(unsigned int, f);
  u += 0x7fffu + ((u >> 16) & 1u);
  return (unsigned short)(u >> 16);
}

// dst[n][k] = src[k][col_off + n], converted to bf16. dims 1024x1024.
__global__ __launch_bounds__(256) void transpose_w(
    const float* __restrict__ src, unsigned short* __restrict__ dst,
    int src_ld, int col_off) {
  int n = blockIdx.x * 16 + threadIdx.x;
  int k = blockIdx.y * 16 + threadIdx.y;
  dst[(size_t)n * C_DIM + k] = f2bf(src[(size_t)k * src_ld + col_off + n]);
}

// ---------------- GEMM1: Khb[b][h][t][64] (bf16) = x(f32) @ Wkt^T + bias --
__global__ __launch_bounds__(256) void gemm_xw(
    const float* __restrict__ A, const unsigned short* __restrict__ Bt,
    const float* __restrict__ bias, unsigned short* __restrict__ out) {
  __shared__ unsigned short Als[128][40];
  __shared__ unsigned short Bls[128][40];
  const int tid = threadIdx.x;
  const int l = tid & 63, w = tid >> 6;
  const int wr = w >> 1, wc = w & 1;
  const int rb = blockIdx.x * 128, cb = blockIdx.y * 128;
  const int srow = tid >> 1, sh = (tid & 1) * 16;
  f32x4 acc[4][4] = {};
  for (int kb = 0; kb < 1024; kb += 32) {
    const f32x4* ap = (const f32x4*)(A + (size_t)(rb + srow) * 1024 + kb + sh);
    f32x4 a0 = ap[0], a1 = ap[1], a2 = ap[2], a3 = ap[3];
    short8 s0, s1;
#pragma unroll
    for (int i = 0; i < 4; ++i) {
      s0[i]     = (short)f2bf(a0[i]);
      s0[i + 4] = (short)f2bf(a1[i]);
      s1[i]     = (short)f2bf(a2[i]);
      s1[i + 4] = (short)f2bf(a3[i]);
    }
    *(short8*)&Als[srow][sh] = s0;
    *(short8*)&Als[srow][sh + 8] = s1;
    const short8* bp = (const short8*)(Bt + (size_t)(cb + srow) * 1024 + kb + sh);
    short8 b0 = bp[0], b1 = bp[1];
    *(short8*)&Bls[srow][sh] = b0;
    *(short8*)&Bls[srow][sh + 8] = b1;
    __syncthreads();
    short8 af[4], bfr[4];
#pragma unroll
    for (int m = 0; m < 4; ++m)
      af[m] = *(const short8*)&Als[wr * 64 + m * 16 + (l & 15)][(l >> 4) * 8];
#pragma unroll
    for (int n = 0; n < 4; ++n)
      bfr[n] = *(const short8*)&Bls[wc * 64 + n * 16 + (l & 15)][(l >> 4) * 8];
#pragma unroll
    for (int m = 0; m < 4; ++m)
#pragma unroll
      for (int n = 0; n < 4; ++n)
        acc[m][n] = __builtin_amdgcn_mfma_f32_16x16x32_bf16(af[m], bfr[n], acc[m][n], 0, 0, 0);
    __syncthreads();
  }
  const int rg = (l >> 4) * 4, cg = l & 15;
#pragma unroll
  for (int m = 0; m < 4; ++m)
#pragma unroll
    for (int n = 0; n < 4; ++n) {
      int col = cb + wc * 64 + n * 16 + cg;
      float bv = bias[col];
#pragma unroll
      for (int r = 0; r < 4; ++r) {
        int row = rb + wr * 64 + m * 16 + rg + r;
        // head-blocked: [b][h][t][d]
        size_t idx = ((size_t)((row >> 11) * 16 + (col >> 6)) * T_SEQ + (row & 2047)) * HD + (col & 63);
        out[idx] = f2bf(acc[m][n][r] + bv);
      }
    }
}

// ---------------- GEMM2: out[8192][1024] (f32) = y(bf16) @ Wpt^T + bias --
__global__ __launch_bounds__(256) void gemm_yw(
    const unsigned short* __restrict__ A, const unsigned short* __restrict__ Bt,
    const float* __restrict__ bias, float* __restrict__ out) {
  __shared__ unsigned short Als[128][40];
  __shared__ unsigned short Bls[128][40];
  const int tid = threadIdx.x;
  const int l = tid & 63, w = tid >> 6;
  const int wr = w >> 1, wc = w & 1;
  const int rb = blockIdx.x * 128, cb = blockIdx.y * 128;
  const int srow = tid >> 1, sh = (tid & 1) * 16;
  f32x4 acc[4][4] = {};
  for (int kb = 0; kb < 1024; kb += 32) {
    const short8* ap = (const short8*)(A + (size_t)(rb + srow) * 1024 + kb + sh);
    short8 a0 = ap[0], a1 = ap[1];
    *(short8*)&Als[srow][sh] = a0;
    *(short8*)&Als[srow][sh + 8] = a1;
    const short8* bp = (const short8*)(Bt + (size_t)(cb + srow) * 1024 + kb + sh);
    short8 b0 = bp[0], b1 = bp[1];
    *(short8*)&Bls[srow][sh] = b0;
    *(short8*)&Bls[srow][sh + 8] = b1;
    __syncthreads();
    short8 af[4], bfr[4];
#pragma unroll
    for (int m = 0; m < 4; ++m)
      af[m] = *(const short8*)&Als[wr * 64 + m * 16 + (l & 15)][(l >> 4) * 8];
#pragma unroll
    for (int n = 0; n < 4; ++n)
      bfr[n] = *(const short8*)&Bls[wc * 64 + n * 16 + (l & 15)][(l >> 4) * 8];
#pragma unroll
    for (int m = 0; m < 4; ++m)
#pragma unroll
      for (int n = 0; n < 4; ++n)
        acc[m][n] = __builtin_amdgcn_mfma_f32_16x16x32_bf16(af[m], bfr[n], acc[m][n], 0, 0, 0);
    __syncthreads();
  }
  const int rg = (l >> 4) * 4, cg = l & 15;
#pragma unroll
  for (int m = 0; m < 4; ++m)
#pragma unroll
    for (int n = 0; n < 4; ++n) {
      int col = cb + wc * 64 + n * 16 + cg;
      float bv = bias[col];
#pragma unroll
      for (int r = 0; r < 4; ++r) {
        int row = rb + wr * 64 + m * 16 + rg + r;
        out[(size_t)row * 1024 + col] = acc[m][n][r] + bv;
      }
    }
}

// ---------------- Flash attention, swapped-QK^T in-register softmax -------
// 8 waves x 16 q-rows = 128 q rows per block; KV tile = 64.
// Khb layout [b*16+h][t][64]. Y written [8192][1024] row-major bf16.
__device__ __forceinline__ void stageV(unsigned short (*Vt)[72],
    const unsigned short* __restrict__ base, int kvb, int sd, int sr) {
  const unsigned short* p = base + (size_t)(kvb + sr) * HD + sd;
  unsigned v0 = *(const unsigned*)(p);
  unsigned v1 = *(const unsigned*)(p + HD);
  unsigned v2 = *(const unsigned*)(p + 2 * HD);
  unsigned v3 = *(const unsigned*)(p + 3 * HD);
  *(unsigned*)&Vt[sd][sr]         = (v0 & 0xffffu) | (v1 << 16);
  *(unsigned*)&Vt[sd + 1][sr]     = (v0 >> 16) | (v1 & 0xffff0000u);
  *(unsigned*)&Vt[sd][sr + 2]     = (v2 & 0xffffu) | (v3 << 16);
  *(unsigned*)&Vt[sd + 1][sr + 2] = (v2 >> 16) | (v3 & 0xffff0000u);
}

__global__ __launch_bounds__(512, 2) void attn_fwd(
    const unsigned short* __restrict__ Khb, unsigned short* __restrict__ Y) {
  const int qt = blockIdx.x & 15;
  const int bh = blockIdx.x >> 4;
  const int tid = threadIdx.x, w = tid >> 6, l = tid & 63;
  const int i = l & 15, g = l >> 4;
  const unsigned short* base = Khb + (size_t)bh * T_SEQ * HD;

  __shared__ unsigned short Vt[2][64][72];

  const int q0w = qt * 128 + w * 16;
  const int qg = q0w + i;
  // Q fragments (B-operand layout): Q[q0w + i][c*32 + g*8 + j]
  short8 qf0 = *(const short8*)(base + (size_t)(q0w + i) * HD + g * 8);
  short8 qf1 = *(const short8*)(base + (size_t)(q0w + i) * HD + 32 + g * 8);

  f32x4 yacc[4] = {};
  float mrun = -INFINITY, lrun = 0.f;

  const int sd = (tid & 31) * 2;   // V^T col pair (d)
  const int sr = (tid >> 5) * 4;   // V^T rows (kv)

  const int nt = qt * 2 + 2;

  stageV(Vt[0], base, 0, sd, sr);
  __syncthreads();

  for (int t = 0; t < nt; ++t) {
    const int kvb = t * 64;
    const int buf = t & 1;
    if (t + 1 < nt) stageV(Vt[buf ^ 1], base, (t + 1) * 64, sd, sr);

    if (kvb <= q0w + 15) {
      // ---- S^T = K Q^T : s[b][r] = S[q0w+i][kvb + 16b + 4g + r]
      f32x4 s[4];
#pragma unroll
      for (int b = 0; b < 4; ++b) {
        const unsigned short* kp = base + (size_t)(kvb + 16 * b + i) * HD + g * 8;
        short8 kf0 = *(const short8*)kp;
        short8 kf1 = *(const short8*)(kp + 32);
        f32x4 acc = {};
        acc = __builtin_amdgcn_mfma_f32_16x16x32_bf16(kf0, qf0, acc, 0, 0, 0);
        acc = __builtin_amdgcn_mfma_f32_16x16x32_bf16(kf1, qf1, acc, 0, 0, 0);
        s[b] = acc;
      }
      const bool needmask = (kvb + 63 > q0w);
#pragma unroll
      for (int b = 0; b < 4; ++b)
#pragma unroll
        for (int r = 0; r < 4; ++r) {
          float v = s[b][r] * 0.125f;
          if (needmask && (kvb + 16 * b + 4 * g + r) > qg) v = -INFINITY;
          s[b][r] = v;
        }
      // ---- tile max (row lives in-lane + groups over shfl_xor 16/32)
      float mt = s[0][0];
#pragma unroll
      for (int b = 0; b < 4; ++b)
#pragma unroll
        for (int r = 0; r < 4; ++r) mt = fmaxf(mt, s[b][r]);
      mt = fmaxf(mt, __shfl_xor(mt, 16));
      mt = fmaxf(mt, __shfl_xor(mt, 32));
      // ---- defer-max online softmax
      if (!__all(mt <= mrun + 8.f)) {
        float mn = fmaxf(mrun, mt);
        float al = __expf(mrun - mn);
        mrun = mn;
        lrun *= al;
        float a0 = __shfl(al, 4 * g + 0);
        float a1 = __shfl(al, 4 * g + 1);
        float a2 = __shfl(al, 4 * g + 2);
        float a3 = __shfl(al, 4 * g + 3);
#pragma unroll
        for (int nb = 0; nb < 4; ++nb) {
          yacc[nb][0] *= a0; yacc[nb][1] *= a1;
          yacc[nb][2] *= a2; yacc[nb][3] *= a3;
        }
      }
      float ps = 0.f;
#pragma unroll
      for (int b = 0; b < 4; ++b)
#pragma unroll
        for (int r = 0; r < 4; ++r) {
          float p = __expf(s[b][r] - mrun);
          s[b][r] = p;
          ps += p;
        }
      ps += __shfl_xor(ps, 16);
      ps += __shfl_xor(ps, 32);
      lrun += ps;
      // ---- pack P to bf16 pairs: pk[b][u] = kv (16b+4g+2u, +2u+1)
      unsigned pk0[2], pk1[2], pk2[2], pk3[2];
      pk0[0] = (unsigned)f2bf(s[0][0]) | ((unsigned)f2bf(s[0][1]) << 16);
      pk0[1] = (unsigned)f2bf(s[0][2]) | ((unsigned)f2bf(s[0][3]) << 16);
      pk1[0] = (unsigned)f2bf(s[1][0]) | ((unsigned)f2bf(s[1][1]) << 16);
      pk1[1] = (unsigned)f2bf(s[1][2]) | ((unsigned)f2bf(s[1][3]) << 16);
      pk2[0] = (unsigned)f2bf(s[2][0]) | ((unsigned)f2bf(s[2][1]) << 16);
      pk2[1] = (unsigned)f2bf(s[2][2]) | ((unsigned)f2bf(s[2][3]) << 16);
      pk3[0] = (unsigned)f2bf(s[3][0]) | ((unsigned)f2bf(s[3][1]) << 16);
      pk3[1] = (unsigned)f2bf(s[3][2]) | ((unsigned)f2bf(s[3][3]) << 16);
      // ---- redistribute to PV A-frags: pa[c] holds P[q][kv=32c+8g+j]
      const int src01 = i + ((g & 1) << 5);
      const int src23 = src01 + 16;
      const bool hi2 = (g >> 1) != 0;
      short8 pa[2];
      {
        unsigned b0u0a = (unsigned)__shfl((int)pk0[0], src01);
        unsigned b1u0a = (unsigned)__shfl((int)pk1[0], src01);
        unsigned b0u1a = (unsigned)__shfl((int)pk0[1], src01);
        unsigned b1u1a = (unsigned)__shfl((int)pk1[1], src01);
        unsigned b0u0b = (unsigned)__shfl((int)pk0[0], src23);
        unsigned b1u0b = (unsigned)__shfl((int)pk1[0], src23);
        unsigned b0u1b = (unsigned)__shfl((int)pk0[1], src23);
        unsigned b1u1b = (unsigned)__shfl((int)pk1[1], src23);
        uint4v u;
        u.x = hi2 ? b1u0a : b0u0a;
        u.y = hi2 ? b1u1a : b0u1a;
        u.z = hi2 ? b1u0b : b0u0b;
        u.w = hi2 ? b1u1b : b0u1b;
        pa[0] = __builtin_bit_cast(short8, u);
      }
      {
        unsigned b0u0a = (unsigned)__shfl((int)pk2[0], src01);
        unsigned b1u0a = (unsigned)__shfl((int)pk3[0], src01);
        unsigned b0u1a = (unsigned)__shfl((int)pk2[1], src01);
        unsigned b1u1a = (unsigned)__shfl((int)pk3[1], src01);
        unsigned b0u0b = (unsigned)__shfl((int)pk2[0], src23);
        unsigned b1u0b = (unsigned)__shfl((int)pk3[0], src23);
        unsigned b0u1b = (unsigned)__shfl((int)pk2[1], src23);
        unsigned b1u1b = (unsigned)__shfl((int)pk3[1], src23);
        uint4v u;
        u.x = hi2 ? b1u0a : b0u0a;
        u.y = hi2 ? b1u1a : b0u1a;
        u.z = hi2 ? b1u0b : b0u0b;
        u.w = hi2 ? b1u1b : b0u1b;
        pa[1] = __builtin_bit_cast(short8, u);
      }
      // ---- y += P @ V  (B-frag from Vt, aligned b128 reads)
#pragma unroll
      for (int c = 0; c < 2; ++c)
#pragma unroll
        for (int nb = 0; nb < 4; ++nb) {
          short8 vf = *(const short8*)&Vt[buf][nb * 16 + i][c * 32 + g * 8];
          yacc[nb] = __builtin_amdgcn_mfma_f32_16x16x32_bf16(pa[c], vf, yacc[nb], 0, 0, 0);
        }
    }
    __syncthreads();
  }

  // ---- epilogue: normalize (1/l shuffled to Y layout) and store
  float linv = 1.f / lrun;
  float l0 = __shfl(linv, 4 * g + 0);
  float l1 = __shfl(linv, 4 * g + 1);
  float l2 = __shfl(linv, 4 * g + 2);
  float l3 = __shfl(linv, 4 * g + 3);
  const int bb = bh >> 4, hh = bh & 15;
  size_t rowbase = ((size_t)bb * T_SEQ + q0w + 4 * g) * C_DIM;
#pragma unroll
  for (int nb = 0; nb < 4; ++nb) {
    int col = hh * 64 + nb * 16 + i;
    Y[rowbase + col]             = f2bf(yacc[nb][0] * l0);
    Y[rowbase + C_DIM + col]     = f2bf(yacc[nb][1] * l1);
    Y[rowbase + 2 * C_DIM + col] = f2bf(yacc[nb][2] * l2);
    Y[rowbase + 3 * C_DIM + col] = f2bf(yacc[nb][3] * l3);
  }
}

extern "C" void kernel_launch(void* const* d_in, const int* in_sizes, int n_in,
                              void* d_out, int out_size, void* d_ws, size_t ws_size,
                              hipStream_t stream) {
  const float* x      = (const float*)d_in[0];
  const float* W_attn = (const float*)d_in[1];
  const float* b_attn = (const float*)d_in[2];
  const float* W_proj = (const float*)d_in[3];
  const float* b_proj = (const float*)d_in[4];
  float* out = (float*)d_out;

  unsigned short* Wkt  = (unsigned short*)d_ws;                 // 1024x1024 bf16
  unsigned short* Wpt  = Wkt + (size_t)1024 * 1024;             // 1024x1024 bf16
  unsigned short* Khb  = Wpt + (size_t)1024 * 1024;             // [64][2048][64] bf16
  unsigned short* Ybuf = Khb + (size_t)8192 * 1024;             // 8192x1024 bf16

  transpose_w<<<dim3(64, 64), dim3(16, 16), 0, stream>>>(W_attn, Wkt, 3072, 1024);
  transpose_w<<<dim3(64, 64), dim3(16, 16), 0, stream>>>(W_proj, Wpt, 1024, 0);

  // K (head-blocked) = x @ Wk + b_attn[C:2C]
  gemm_xw<<<dim3(64, 8), 256, 0, stream>>>(x, Wkt, b_attn + 1024, Khb);

  // y = causal_attn(K,K,K)
  attn_fwd<<<dim3(1024), 512, 0, stream>>>(Khb, Ybuf);

  // out = y @ Wp + b_proj
  gemm_yw<<<dim3(64, 8), 256, 0, stream>>>(Ybuf, Wpt, b_proj, out);
}

// Round 4
// 242.317 us; speedup vs baseline: 1.4441x; 1.3687x over previous
//
#include <hip/hip_runtime.h>

#define T_SEQ 2048
#define C_DIM 1024
#define HD 64

typedef __attribute__((ext_vector_type(8))) short short8;
typedef __attribute__((ext_vector_type(4))) float f32x4;
typedef __attribute__((ext_vector_type(4))) unsigned int uint4v;

extern "C" __device__ float __ocml_native_exp2_f32(float);

__device__ __forceinline__ unsigned short f2bf(float f) {
  unsigned int u = __builtin_bit_cast(unsigned int, f);
  u += 0x7fffu + ((u >> 16) & 1u);
  return (unsigned short)(u >> 16);
}

__device__ __forceinline__ unsigned cvt_pk_bf16(float lo, float hi) {
  unsigned r;
  asm("v_cvt_pk_bf16_f32 %0, %1, %2" : "=v"(r) : "v"(lo), "v"(hi));
  return r;
}

// dst[n][k] = src[k][col_off + n], converted to bf16. dims 1024x1024.
__global__ __launch_bounds__(256) void transpose_w(
    const float* __restrict__ src, unsigned short* __restrict__ dst,
    int src_ld, int col_off) {
  int n = blockIdx.x * 16 + threadIdx.x;
  int k = blockIdx.y * 16 + threadIdx.y;
  dst[(size_t)n * C_DIM + k] = f2bf(src[(size_t)k * src_ld + col_off + n]);
}

// ---- GEMM1: Khb[bh][t][d] and Vt[bh][d][t] (bf16) = x(f32) @ Wkt^T + bias
__global__ __launch_bounds__(256) void gemm_xw(
    const float* __restrict__ A, const unsigned short* __restrict__ Bt,
    const float* __restrict__ bias, unsigned short* __restrict__ out,
    unsigned short* __restrict__ vt) {
  __shared__ unsigned short Als[128][40];
  __shared__ unsigned short Bls[128][40];
  const int tid = threadIdx.x;
  const int l = tid & 63, w = tid >> 6;
  const int wr = w >> 1, wc = w & 1;
  const int rb = blockIdx.x * 128, cb = blockIdx.y * 128;
  const int srow = tid >> 1, sh = (tid & 1) * 16;
  f32x4 acc[4][4] = {};
  for (int kb = 0; kb < 1024; kb += 32) {
    const f32x4* ap = (const f32x4*)(A + (size_t)(rb + srow) * 1024 + kb + sh);
    f32x4 a0 = ap[0], a1 = ap[1], a2 = ap[2], a3 = ap[3];
    short8 s0, s1;
#pragma unroll
    for (int i = 0; i < 4; ++i) {
      s0[i]     = (short)f2bf(a0[i]);
      s0[i + 4] = (short)f2bf(a1[i]);
      s1[i]     = (short)f2bf(a2[i]);
      s1[i + 4] = (short)f2bf(a3[i]);
    }
    *(short8*)&Als[srow][sh] = s0;
    *(short8*)&Als[srow][sh + 8] = s1;
    const short8* bp = (const short8*)(Bt + (size_t)(cb + srow) * 1024 + kb + sh);
    short8 b0 = bp[0], b1 = bp[1];
    *(short8*)&Bls[srow][sh] = b0;
    *(short8*)&Bls[srow][sh + 8] = b1;
    __syncthreads();
    short8 af[4], bfr[4];
#pragma unroll
    for (int m = 0; m < 4; ++m)
      af[m] = *(const short8*)&Als[wr * 64 + m * 16 + (l & 15)][(l >> 4) * 8];
#pragma unroll
    for (int n = 0; n < 4; ++n)
      bfr[n] = *(const short8*)&Bls[wc * 64 + n * 16 + (l & 15)][(l >> 4) * 8];
#pragma unroll
    for (int m = 0; m < 4; ++m)
#pragma unroll
      for (int n = 0; n < 4; ++n)
        acc[m][n] = __builtin_amdgcn_mfma_f32_16x16x32_bf16(af[m], bfr[n], acc[m][n], 0, 0, 0);
    __syncthreads();
  }
  const int rg = (l >> 4) * 4, cg = l & 15;
#pragma unroll
  for (int m = 0; m < 4; ++m)
#pragma unroll
    for (int n = 0; n < 4; ++n) {
      int col = cb + wc * 64 + n * 16 + cg;
      float bv = bias[col];
      int row0 = rb + wr * 64 + m * 16 + rg;
      unsigned short e0 = f2bf(acc[m][n][0] + bv);
      unsigned short e1 = f2bf(acc[m][n][1] + bv);
      unsigned short e2 = f2bf(acc[m][n][2] + bv);
      unsigned short e3 = f2bf(acc[m][n][3] + bv);
      size_t bhd = (size_t)((row0 >> 11) * 16 + (col >> 6));
      size_t kidx = (bhd * T_SEQ + (row0 & 2047)) * HD + (col & 63);
      out[kidx]          = e0;
      out[kidx + HD]     = e1;
      out[kidx + 2 * HD] = e2;
      out[kidx + 3 * HD] = e3;
      unsigned long long pv = (unsigned long long)e0 | ((unsigned long long)e1 << 16)
                            | ((unsigned long long)e2 << 32) | ((unsigned long long)e3 << 48);
      *(unsigned long long*)&vt[(bhd * HD + (col & 63)) * T_SEQ + (row0 & 2047)] = pv;
    }
}

// ---- GEMM2: out[8192][1024] (f32) = y(bf16) @ Wpt^T + bias
__global__ __launch_bounds__(256) void gemm_yw(
    const unsigned short* __restrict__ A, const unsigned short* __restrict__ Bt,
    const float* __restrict__ bias, float* __restrict__ out) {
  __shared__ unsigned short Als[128][40];
  __shared__ unsigned short Bls[128][40];
  const int tid = threadIdx.x;
  const int l = tid & 63, w = tid >> 6;
  const int wr = w >> 1, wc = w & 1;
  const int rb = blockIdx.x * 128, cb = blockIdx.y * 128;
  const int srow = tid >> 1, sh = (tid & 1) * 16;
  f32x4 acc[4][4] = {};
  for (int kb = 0; kb < 1024; kb += 32) {
    const short8* ap = (const short8*)(A + (size_t)(rb + srow) * 1024 + kb + sh);
    short8 a0 = ap[0], a1 = ap[1];
    *(short8*)&Als[srow][sh] = a0;
    *(short8*)&Als[srow][sh + 8] = a1;
    const short8* bp = (const short8*)(Bt + (size_t)(cb + srow) * 1024 + kb + sh);
    short8 b0 = bp[0], b1 = bp[1];
    *(short8*)&Bls[srow][sh] = b0;
    *(short8*)&Bls[srow][sh + 8] = b1;
    __syncthreads();
    short8 af[4], bfr[4];
#pragma unroll
    for (int m = 0; m < 4; ++m)
      af[m] = *(const short8*)&Als[wr * 64 + m * 16 + (l & 15)][(l >> 4) * 8];
#pragma unroll
    for (int n = 0; n < 4; ++n)
      bfr[n] = *(const short8*)&Bls[wc * 64 + n * 16 + (l & 15)][(l >> 4) * 8];
#pragma unroll
    for (int m = 0; m < 4; ++m)
#pragma unroll
      for (int n = 0; n < 4; ++n)
        acc[m][n] = __builtin_amdgcn_mfma_f32_16x16x32_bf16(af[m], bfr[n], acc[m][n], 0, 0, 0);
    __syncthreads();
  }
  const int rg = (l >> 4) * 4, cg = l & 15;
#pragma unroll
  for (int m = 0; m < 4; ++m)
#pragma unroll
    for (int n = 0; n < 4; ++n) {
      int col = cb + wc * 64 + n * 16 + cg;
      float bv = bias[col];
#pragma unroll
      for (int r = 0; r < 4; ++r) {
        int row = rb + wr * 64 + m * 16 + rg + r;
        out[(size_t)row * 1024 + col] = acc[m][n][r] + bv;
      }
    }
}

// ---- Flash attention, barrier-free, no LDS. 4 waves x 32 q = 128 q/block.
// log2-domain softmax. Khb[bh][t][d], Vt[bh][d][t].
__device__ __forceinline__ void sm_group(
    f32x4 (&s)[4], int qq, int kvb, bool needmask, int g,
    float& mrun, float& lrun, f32x4 (&yacc)[4],
    int src01, int src23, bool hi2, short8 (&pa)[2]) {
  if (needmask) {
    const int lim = qq - kvb;
#pragma unroll
    for (int b = 0; b < 4; ++b)
#pragma unroll
      for (int r = 0; r < 4; ++r)
        if (16 * b + 4 * g + r > lim) s[b][r] = -INFINITY;
  }
  float mt = fmaxf(fmaxf(s[0][0], s[0][1]), fmaxf(s[0][2], s[0][3]));
#pragma unroll
  for (int b = 1; b < 4; ++b)
    mt = fmaxf(mt, fmaxf(fmaxf(s[b][0], s[b][1]), fmaxf(s[b][2], s[b][3])));
  mt = fmaxf(mt, __shfl_xor(mt, 16));
  mt = fmaxf(mt, __shfl_xor(mt, 32));
  if (!__all(mt <= mrun + 11.5416f)) {   // 8 nats in log2 units
    float mn = fmaxf(mrun, mt);
    float al = __ocml_native_exp2_f32(mrun - mn);
    mrun = mn;
    lrun *= al;
    float a0 = __shfl(al, 4 * g + 0);
    float a1 = __shfl(al, 4 * g + 1);
    float a2 = __shfl(al, 4 * g + 2);
    float a3 = __shfl(al, 4 * g + 3);
#pragma unroll
    for (int nb = 0; nb < 4; ++nb) {
      yacc[nb][0] *= a0; yacc[nb][1] *= a1;
      yacc[nb][2] *= a2; yacc[nb][3] *= a3;
    }
  }
  float ps = 0.f;
  unsigned pk[4][2];
#pragma unroll
  for (int b = 0; b < 4; ++b) {
    float p0 = __ocml_native_exp2_f32(s[b][0] - mrun);
    float p1 = __ocml_native_exp2_f32(s[b][1] - mrun);
    float p2 = __ocml_native_exp2_f32(s[b][2] - mrun);
    float p3 = __ocml_native_exp2_f32(s[b][3] - mrun);
    ps += (p0 + p1) + (p2 + p3);
    pk[b][0] = cvt_pk_bf16(p0, p1);
    pk[b][1] = cvt_pk_bf16(p2, p3);
  }
  ps += __shfl_xor(ps, 16);
  ps += __shfl_xor(ps, 32);
  lrun += ps;
  {
    unsigned x0a = (unsigned)__shfl((int)pk[0][0], src01);
    unsigned x1a = (unsigned)__shfl((int)pk[1][0], src01);
    unsigned x0b = (unsigned)__shfl((int)pk[0][1], src01);
    unsigned x1b = (unsigned)__shfl((int)pk[1][1], src01);
    unsigned y0a = (unsigned)__shfl((int)pk[0][0], src23);
    unsigned y1a = (unsigned)__shfl((int)pk[1][0], src23);
    unsigned y0b = (unsigned)__shfl((int)pk[0][1], src23);
    unsigned y1b = (unsigned)__shfl((int)pk[1][1], src23);
    uint4v u;
    u.x = hi2 ? x1a : x0a;
    u.y = hi2 ? x1b : x0b;
    u.z = hi2 ? y1a : y0a;
    u.w = hi2 ? y1b : y0b;
    pa[0] = __builtin_bit_cast(short8, u);
  }
  {
    unsigned x0a = (unsigned)__shfl((int)pk[2][0], src01);
    unsigned x1a = (unsigned)__shfl((int)pk[3][0], src01);
    unsigned x0b = (unsigned)__shfl((int)pk[2][1], src01);
    unsigned x1b = (unsigned)__shfl((int)pk[3][1], src01);
    unsigned y0a = (unsigned)__shfl((int)pk[2][0], src23);
    unsigned y1a = (unsigned)__shfl((int)pk[3][0], src23);
    unsigned y0b = (unsigned)__shfl((int)pk[2][1], src23);
    unsigned y1b = (unsigned)__shfl((int)pk[3][1], src23);
    uint4v u;
    u.x = hi2 ? x1a : x0a;
    u.y = hi2 ? x1b : x0b;
    u.z = hi2 ? y1a : y0a;
    u.w = hi2 ? y1b : y0b;
    pa[1] = __builtin_bit_cast(short8, u);
  }
}

__global__ __launch_bounds__(256, 4) void attn_fwd(
    const unsigned short* __restrict__ Khb, const unsigned short* __restrict__ Vt,
    unsigned short* __restrict__ Y) {
  const int qt = blockIdx.x >> 6;     // balanced: CU gets qt {q,q+4,q+8,q+12}
  const int bh = blockIdx.x & 63;
  const int tid = threadIdx.x, w = tid >> 6, l = tid & 63;
  const int i = l & 15, g = l >> 4;
  const unsigned short* kbase = Khb + (size_t)bh * T_SEQ * HD;
  const unsigned short* vbase = Vt + (size_t)bh * HD * T_SEQ;

  const int q0 = qt * 128 + w * 32;
  const int qA = q0 + i, qB = q0 + 16 + i;

  short8 qa0 = *(const short8*)(kbase + (size_t)qA * HD + g * 8);
  short8 qa1 = *(const short8*)(kbase + (size_t)qA * HD + 32 + g * 8);
  short8 qb0 = *(const short8*)(kbase + (size_t)qB * HD + g * 8);
  short8 qb1 = *(const short8*)(kbase + (size_t)qB * HD + 32 + g * 8);

  f32x4 ya[4] = {}, yb[4] = {};
  float mA = -INFINITY, lA = 0.f, mB = -INFINITY, lB = 0.f;

  const int nt = (q0 + 31) / 64 + 1;
  const int src01 = i + ((g & 1) << 5);
  const int src23 = src01 + 16;
  const bool hi2 = (g >> 1) != 0;
  const float SCL = 0.18033688f;   // 0.125 * log2(e)

  for (int t = 0; t < nt; ++t) {
    const int kvb = t * 64;
    f32x4 sa[4], sb[4];
#pragma unroll
    for (int b = 0; b < 4; ++b) {
      const unsigned short* kp = kbase + (size_t)(kvb + 16 * b + i) * HD + g * 8;
      short8 k0 = *(const short8*)kp;
      short8 k1 = *(const short8*)(kp + 32);
      f32x4 acc = {};
      acc = __builtin_amdgcn_mfma_f32_16x16x32_bf16(k0, qa0, acc, 0, 0, 0);
      acc = __builtin_amdgcn_mfma_f32_16x16x32_bf16(k1, qa1, acc, 0, 0, 0);
      sa[b] = acc;
      f32x4 acc2 = {};
      acc2 = __builtin_amdgcn_mfma_f32_16x16x32_bf16(k0, qb0, acc2, 0, 0, 0);
      acc2 = __builtin_amdgcn_mfma_f32_16x16x32_bf16(k1, qb1, acc2, 0, 0, 0);
      sb[b] = acc2;
    }
#pragma unroll
    for (int b = 0; b < 4; ++b)
#pragma unroll
      for (int r = 0; r < 4; ++r) { sa[b][r] *= SCL; sb[b][r] *= SCL; }

    const bool needmask = (kvb + 63 > q0);
    short8 paA[2], paB[2];
    sm_group(sa, qA, kvb, needmask, g, mA, lA, ya, src01, src23, hi2, paA);
    sm_group(sb, qB, kvb, needmask, g, mB, lB, yb, src01, src23, hi2, paB);

#pragma unroll
    for (int c = 0; c < 2; ++c)
#pragma unroll
      for (int nb = 0; nb < 4; ++nb) {
        short8 vf = *(const short8*)(vbase + (size_t)(nb * 16 + i) * T_SEQ + kvb + c * 32 + g * 8);
        ya[nb] = __builtin_amdgcn_mfma_f32_16x16x32_bf16(paA[c], vf, ya[nb], 0, 0, 0);
        yb[nb] = __builtin_amdgcn_mfma_f32_16x16x32_bf16(paB[c], vf, yb[nb], 0, 0, 0);
      }
  }

  const int bb = bh >> 4, hh = bh & 15;
  float liA = 1.f / lA;
  float lA0 = __shfl(liA, 4 * g + 0);
  float lA1 = __shfl(liA, 4 * g + 1);
  float lA2 = __shfl(liA, 4 * g + 2);
  float lA3 = __shfl(liA, 4 * g + 3);
  size_t rowbase = ((size_t)bb * T_SEQ + q0 + 4 * g) * C_DIM;
#pragma unroll
  for (int nb = 0; nb < 4; ++nb) {
    int col = hh * 64 + nb * 16 + i;
    Y[rowbase + col]             = f2bf(ya[nb][0] * lA0);
    Y[rowbase + C_DIM + col]     = f2bf(ya[nb][1] * lA1);
    Y[rowbase + 2 * C_DIM + col] = f2bf(ya[nb][2] * lA2);
    Y[rowbase + 3 * C_DIM + col] = f2bf(ya[nb][3] * lA3);
  }
  float liB = 1.f / lB;
  float lB0 = __shfl(liB, 4 * g + 0);
  float lB1 = __shfl(liB, 4 * g + 1);
  float lB2 = __shfl(liB, 4 * g + 2);
  float lB3 = __shfl(liB, 4 * g + 3);
  rowbase += (size_t)16 * C_DIM;
#pragma unroll
  for (int nb = 0; nb < 4; ++nb) {
    int col = hh * 64 + nb * 16 + i;
    Y[rowbase + col]             = f2bf(yb[nb][0] * lB0);
    Y[rowbase + C_DIM + col]     = f2bf(yb[nb][1] * lB1);
    Y[rowbase + 2 * C_DIM + col] = f2bf(yb[nb][2] * lB2);
    Y[rowbase + 3 * C_DIM + col] = f2bf(yb[nb][3] * lB3);
  }
}

extern "C" void kernel_launch(void* const* d_in, const int* in_sizes, int n_in,
                              void* d_out, int out_size, void* d_ws, size_t ws_size,
                              hipStream_t stream) {
  const float* x      = (const float*)d_in[0];
  const float* W_attn = (const float*)d_in[1];
  const float* b_attn = (const float*)d_in[2];
  const float* W_proj = (const float*)d_in[3];
  const float* b_proj = (const float*)d_in[4];
  float* out = (float*)d_out;

  unsigned short* Wkt  = (unsigned short*)d_ws;                 // 1024x1024 bf16
  unsigned short* Wpt  = Wkt + (size_t)1024 * 1024;             // 1024x1024 bf16
  unsigned short* Khb  = Wpt + (size_t)1024 * 1024;             // [64][2048][64] bf16
  unsigned short* Ybuf = Khb + (size_t)8192 * 1024;             // 8192x1024 bf16
  unsigned short* Vtb  = Ybuf + (size_t)8192 * 1024;            // [64][64][2048] bf16

  transpose_w<<<dim3(64, 64), dim3(16, 16), 0, stream>>>(W_attn, Wkt, 3072, 1024);
  transpose_w<<<dim3(64, 64), dim3(16, 16), 0, stream>>>(W_proj, Wpt, 1024, 0);

  // K (head-blocked) + V^T = x @ Wk + b_attn[C:2C]
  gemm_xw<<<dim3(64, 8), 256, 0, stream>>>(x, Wkt, b_attn + 1024, Khb, Vtb);

  // y = causal_attn(K,K,K)
  attn_fwd<<<dim3(1024), 256, 0, stream>>>(Khb, Vtb, Ybuf);

  // out = y @ Wp + b_proj
  gemm_yw<<<dim3(64, 8), 256, 0, stream>>>(Ybuf, Wpt, b_proj, out);
}

// Round 7
// 240.637 us; speedup vs baseline: 1.4542x; 1.0070x over previous
//
#include <hip/hip_runtime.h>

#define T_SEQ 2048
#define C_DIM 1024
#define HD 64

typedef __attribute__((ext_vector_type(8))) short short8;
typedef __attribute__((ext_vector_type(4))) float f32x4;
typedef __attribute__((ext_vector_type(4))) unsigned int uint4v;

extern "C" __device__ float __ocml_native_exp2_f32(float);

__device__ __forceinline__ unsigned short f2bf(float f) {
  unsigned int u = __builtin_bit_cast(unsigned int, f);
  u += 0x7fffu + ((u >> 16) & 1u);
  return (unsigned short)(u >> 16);
}

__device__ __forceinline__ unsigned cvt_pk_bf16(float lo, float hi) {
  unsigned r;
  asm("v_cvt_pk_bf16_f32 %0, %1, %2" : "=v"(r) : "v"(lo), "v"(hi));
  return r;
}

// dst[n][k] = src[k][col_off + n], converted to bf16. dims 1024x1024.
__global__ __launch_bounds__(256) void transpose_w(
    const float* __restrict__ src, unsigned short* __restrict__ dst,
    int src_ld, int col_off) {
  int n = blockIdx.x * 16 + threadIdx.x;
  int k = blockIdx.y * 16 + threadIdx.y;
  dst[(size_t)n * C_DIM + k] = f2bf(src[(size_t)k * src_ld + col_off + n]);
}

// ---- GEMM1: Khb[bh][t][d] and Vt[bh][d][t] (bf16) = x(f32) @ Wkt^T + bias
__global__ __launch_bounds__(256) void gemm_xw(
    const float* __restrict__ A, const unsigned short* __restrict__ Bt,
    const float* __restrict__ bias, unsigned short* __restrict__ out,
    unsigned short* __restrict__ vt) {
  __shared__ unsigned short Als[128][40];
  __shared__ unsigned short Bls[128][40];
  const int tid = threadIdx.x;
  const int l = tid & 63, w = tid >> 6;
  const int wr = w >> 1, wc = w & 1;
  const int rb = blockIdx.x * 128, cb = blockIdx.y * 128;
  const int srow = tid >> 1, sh = (tid & 1) * 16;
  f32x4 acc[4][4] = {};
  for (int kb = 0; kb < 1024; kb += 32) {
    const f32x4* ap = (const f32x4*)(A + (size_t)(rb + srow) * 1024 + kb + sh);
    f32x4 a0 = ap[0], a1 = ap[1], a2 = ap[2], a3 = ap[3];
    short8 s0, s1;
#pragma unroll
    for (int i = 0; i < 4; ++i) {
      s0[i]     = (short)f2bf(a0[i]);
      s0[i + 4] = (short)f2bf(a1[i]);
      s1[i]     = (short)f2bf(a2[i]);
      s1[i + 4] = (short)f2bf(a3[i]);
    }
    *(short8*)&Als[srow][sh] = s0;
    *(short8*)&Als[srow][sh + 8] = s1;
    const short8* bp = (const short8*)(Bt + (size_t)(cb + srow) * 1024 + kb + sh);
    short8 b0 = bp[0], b1 = bp[1];
    *(short8*)&Bls[srow][sh] = b0;
    *(short8*)&Bls[srow][sh + 8] = b1;
    __syncthreads();
    short8 af[4], bfr[4];
#pragma unroll
    for (int m = 0; m < 4; ++m)
      af[m] = *(const short8*)&Als[wr * 64 + m * 16 + (l & 15)][(l >> 4) * 8];
#pragma unroll
    for (int n = 0; n < 4; ++n)
      bfr[n] = *(const short8*)&Bls[wc * 64 + n * 16 + (l & 15)][(l >> 4) * 8];
#pragma unroll
    for (int m = 0; m < 4; ++m)
#pragma unroll
      for (int n = 0; n < 4; ++n)
        acc[m][n] = __builtin_amdgcn_mfma_f32_16x16x32_bf16(af[m], bfr[n], acc[m][n], 0, 0, 0);
    __syncthreads();
  }
  const int rg = (l >> 4) * 4, cg = l & 15;
#pragma unroll
  for (int m = 0; m < 4; ++m)
#pragma unroll
    for (int n = 0; n < 4; ++n) {
      int col = cb + wc * 64 + n * 16 + cg;
      float bv = bias[col];
      int row0 = rb + wr * 64 + m * 16 + rg;
      unsigned short e0 = f2bf(acc[m][n][0] + bv);
      unsigned short e1 = f2bf(acc[m][n][1] + bv);
      unsigned short e2 = f2bf(acc[m][n][2] + bv);
      unsigned short e3 = f2bf(acc[m][n][3] + bv);
      size_t bhd = (size_t)((row0 >> 11) * 16 + (col >> 6));
      size_t kidx = (bhd * T_SEQ + (row0 & 2047)) * HD + (col & 63);
      out[kidx]          = e0;
      out[kidx + HD]     = e1;
      out[kidx + 2 * HD] = e2;
      out[kidx + 3 * HD] = e3;
      unsigned long long pv = (unsigned long long)e0 | ((unsigned long long)e1 << 16)
                            | ((unsigned long long)e2 << 32) | ((unsigned long long)e3 << 48);
      *(unsigned long long*)&vt[(bhd * HD + (col & 63)) * T_SEQ + (row0 & 2047)] = pv;
    }
}

// ---- GEMM2: out[8192][1024] (f32) = y(bf16) @ Wpt^T + bias
__global__ __launch_bounds__(256) void gemm_yw(
    const unsigned short* __restrict__ A, const unsigned short* __restrict__ Bt,
    const float* __restrict__ bias, float* __restrict__ out) {
  __shared__ unsigned short Als[128][40];
  __shared__ unsigned short Bls[128][40];
  const int tid = threadIdx.x;
  const int l = tid & 63, w = tid >> 6;
  const int wr = w >> 1, wc = w & 1;
  const int rb = blockIdx.x * 128, cb = blockIdx.y * 128;
  const int srow = tid >> 1, sh = (tid & 1) * 16;
  f32x4 acc[4][4] = {};
  for (int kb = 0; kb < 1024; kb += 32) {
    const short8* ap = (const short8*)(A + (size_t)(rb + srow) * 1024 + kb + sh);
    short8 a0 = ap[0], a1 = ap[1];
    *(short8*)&Als[srow][sh] = a0;
    *(short8*)&Als[srow][sh + 8] = a1;
    const short8* bp = (const short8*)(Bt + (size_t)(cb + srow) * 1024 + kb + sh);
    short8 b0 = bp[0], b1 = bp[1];
    *(short8*)&Bls[srow][sh] = b0;
    *(short8*)&Bls[srow][sh + 8] = b1;
    __syncthreads();
    short8 af[4], bfr[4];
#pragma unroll
    for (int m = 0; m < 4; ++m)
      af[m] = *(const short8*)&Als[wr * 64 + m * 16 + (l & 15)][(l >> 4) * 8];
#pragma unroll
    for (int n = 0; n < 4; ++n)
      bfr[n] = *(const short8*)&Bls[wc * 64 + n * 16 + (l & 15)][(l >> 4) * 8];
#pragma unroll
    for (int m = 0; m < 4; ++m)
#pragma unroll
      for (int n = 0; n < 4; ++n)
        acc[m][n] = __builtin_amdgcn_mfma_f32_16x16x32_bf16(af[m], bfr[n], acc[m][n], 0, 0, 0);
    __syncthreads();
  }
  const int rg = (l >> 4) * 4, cg = l & 15;
#pragma unroll
  for (int m = 0; m < 4; ++m)
#pragma unroll
    for (int n = 0; n < 4; ++n) {
      int col = cb + wc * 64 + n * 16 + cg;
      float bv = bias[col];
#pragma unroll
      for (int r = 0; r < 4; ++r) {
        int row = rb + wr * 64 + m * 16 + rg + r;
        out[(size_t)row * 1024 + col] = acc[m][n][r] + bv;
      }
    }
}

// ---- Flash attention (verified round-4 math), 1 wave per block.
// Block = one 32-row q-chunk of one (b,h). Grid = 64 chunks x 64 bh = 4096.
// Blocks ordered by DESCENDING work so long chunks start first; HW backfills.
__device__ __forceinline__ void sm_group(
    f32x4 (&s)[4], int qq, int kvb, bool needmask, int g,
    float& mrun, float& lrun, f32x4 (&yacc)[4],
    int src01, int src23, bool hi2, short8 (&pa)[2]) {
  if (needmask) {
    const int lim = qq - kvb;
#pragma unroll
    for (int b = 0; b < 4; ++b)
#pragma unroll
      for (int r = 0; r < 4; ++r)
        if (16 * b + 4 * g + r > lim) s[b][r] = -INFINITY;
  }
  float mt = fmaxf(fmaxf(s[0][0], s[0][1]), fmaxf(s[0][2], s[0][3]));
#pragma unroll
  for (int b = 1; b < 4; ++b)
    mt = fmaxf(mt, fmaxf(fmaxf(s[b][0], s[b][1]), fmaxf(s[b][2], s[b][3])));
  mt = fmaxf(mt, __shfl_xor(mt, 16));
  mt = fmaxf(mt, __shfl_xor(mt, 32));
  if (!__all(mt <= mrun + 11.5416f)) {   // 8 nats in log2 units
    float mn = fmaxf(mrun, mt);
    float al = __ocml_native_exp2_f32(mrun - mn);
    mrun = mn;
    lrun *= al;
    float a0 = __shfl(al, 4 * g + 0);
    float a1 = __shfl(al, 4 * g + 1);
    float a2 = __shfl(al, 4 * g + 2);
    float a3 = __shfl(al, 4 * g + 3);
#pragma unroll
    for (int nb = 0; nb < 4; ++nb) {
      yacc[nb][0] *= a0; yacc[nb][1] *= a1;
      yacc[nb][2] *= a2; yacc[nb][3] *= a3;
    }
  }
  float ps = 0.f;
  unsigned pk[4][2];
#pragma unroll
  for (int b = 0; b < 4; ++b) {
    float p0 = __ocml_native_exp2_f32(s[b][0] - mrun);
    float p1 = __ocml_native_exp2_f32(s[b][1] - mrun);
    float p2 = __ocml_native_exp2_f32(s[b][2] - mrun);
    float p3 = __ocml_native_exp2_f32(s[b][3] - mrun);
    ps += (p0 + p1) + (p2 + p3);
    pk[b][0] = cvt_pk_bf16(p0, p1);
    pk[b][1] = cvt_pk_bf16(p2, p3);
  }
  ps += __shfl_xor(ps, 16);
  ps += __shfl_xor(ps, 32);
  lrun += ps;
  {
    unsigned x0a = (unsigned)__shfl((int)pk[0][0], src01);
    unsigned x1a = (unsigned)__shfl((int)pk[1][0], src01);
    unsigned x0b = (unsigned)__shfl((int)pk[0][1], src01);
    unsigned x1b = (unsigned)__shfl((int)pk[1][1], src01);
    unsigned y0a = (unsigned)__shfl((int)pk[0][0], src23);
    unsigned y1a = (unsigned)__shfl((int)pk[1][0], src23);
    unsigned y0b = (unsigned)__shfl((int)pk[0][1], src23);
    unsigned y1b = (unsigned)__shfl((int)pk[1][1], src23);
    uint4v u;
    u.x = hi2 ? x1a : x0a;
    u.y = hi2 ? x1b : x0b;
    u.z = hi2 ? y1a : y0a;
    u.w = hi2 ? y1b : y0b;
    pa[0] = __builtin_bit_cast(short8, u);
  }
  {
    unsigned x0a = (unsigned)__shfl((int)pk[2][0], src01);
    unsigned x1a = (unsigned)__shfl((int)pk[3][0], src01);
    unsigned x0b = (unsigned)__shfl((int)pk[2][1], src01);
    unsigned x1b = (unsigned)__shfl((int)pk[3][1], src01);
    unsigned y0a = (unsigned)__shfl((int)pk[2][0], src23);
    unsigned y1a = (unsigned)__shfl((int)pk[3][0], src23);
    unsigned y0b = (unsigned)__shfl((int)pk[2][1], src23);
    unsigned y1b = (unsigned)__shfl((int)pk[3][1], src23);
    uint4v u;
    u.x = hi2 ? x1a : x0a;
    u.y = hi2 ? x1b : x0b;
    u.z = hi2 ? y1a : y0a;
    u.w = hi2 ? y1b : y0b;
    pa[1] = __builtin_bit_cast(short8, u);
  }
}

__global__ __launch_bounds__(64, 4) void attn_fwd(
    const unsigned short* __restrict__ Khb, const unsigned short* __restrict__ Vt,
    unsigned short* __restrict__ Y) {
  const int id = blockIdx.x;
  const int bh = id & 63;
  const int chunk = 63 - (id >> 6);    // descending work order
  const int l = threadIdx.x & 63;
  const int i = l & 15, g = l >> 4;
  const unsigned short* kbase = Khb + (size_t)bh * T_SEQ * HD;
  const unsigned short* vbase = Vt + (size_t)bh * HD * T_SEQ;

  const int q0 = chunk * 32;
  const int qA = q0 + i, qB = q0 + 16 + i;

  short8 qa0 = *(const short8*)(kbase + (size_t)qA * HD + g * 8);
  short8 qa1 = *(const short8*)(kbase + (size_t)qA * HD + 32 + g * 8);
  short8 qb0 = *(const short8*)(kbase + (size_t)qB * HD + g * 8);
  short8 qb1 = *(const short8*)(kbase + (size_t)qB * HD + 32 + g * 8);

  f32x4 ya[4] = {}, yb[4] = {};
  float mA = -INFINITY, lA = 0.f, mB = -INFINITY, lB = 0.f;

  const int nt = (q0 + 31) / 64 + 1;
  const int src01 = i + ((g & 1) << 5);
  const int src23 = src01 + 16;
  const bool hi2 = (g >> 1) != 0;
  const float SCL = 0.18033688f;   // 0.125 * log2(e)

  for (int t = 0; t < nt; ++t) {
    const int kvb = t * 64;
    f32x4 sa[4], sb[4];
#pragma unroll
    for (int b = 0; b < 4; ++b) {
      const unsigned short* kp = kbase + (size_t)(kvb + 16 * b + i) * HD + g * 8;
      short8 k0 = *(const short8*)kp;
      short8 k1 = *(const short8*)(kp + 32);
      f32x4 acc = {};
      acc = __builtin_amdgcn_mfma_f32_16x16x32_bf16(k0, qa0, acc, 0, 0, 0);
      acc = __builtin_amdgcn_mfma_f32_16x16x32_bf16(k1, qa1, acc, 0, 0, 0);
      sa[b] = acc;
      f32x4 acc2 = {};
      acc2 = __builtin_amdgcn_mfma_f32_16x16x32_bf16(k0, qb0, acc2, 0, 0, 0);
      acc2 = __builtin_amdgcn_mfma_f32_16x16x32_bf16(k1, qb1, acc2, 0, 0, 0);
      sb[b] = acc2;
    }
#pragma unroll
    for (int b = 0; b < 4; ++b)
#pragma unroll
      for (int r = 0; r < 4; ++r) { sa[b][r] *= SCL; sb[b][r] *= SCL; }

    const bool needmask = (kvb + 63 > q0);
    short8 paA[2], paB[2];
    sm_group(sa, qA, kvb, needmask, g, mA, lA, ya, src01, src23, hi2, paA);
    sm_group(sb, qB, kvb, needmask, g, mB, lB, yb, src01, src23, hi2, paB);

#pragma unroll
    for (int c = 0; c < 2; ++c)
#pragma unroll
      for (int nb = 0; nb < 4; ++nb) {
        short8 vf = *(const short8*)(vbase + (size_t)(nb * 16 + i) * T_SEQ + kvb + c * 32 + g * 8);
        ya[nb] = __builtin_amdgcn_mfma_f32_16x16x32_bf16(paA[c], vf, ya[nb], 0, 0, 0);
        yb[nb] = __builtin_amdgcn_mfma_f32_16x16x32_bf16(paB[c], vf, yb[nb], 0, 0, 0);
      }
  }

  const int bb = bh >> 4, hh = bh & 15;
  float liA = 1.f / lA;
  float lA0 = __shfl(liA, 4 * g + 0);
  float lA1 = __shfl(liA, 4 * g + 1);
  float lA2 = __shfl(liA, 4 * g + 2);
  float lA3 = __shfl(liA, 4 * g + 3);
  size_t rowbase = ((size_t)bb * T_SEQ + q0 + 4 * g) * C_DIM;
#pragma unroll
  for (int nb = 0; nb < 4; ++nb) {
    int col = hh * 64 + nb * 16 + i;
    Y[rowbase + col]             = f2bf(ya[nb][0] * lA0);
    Y[rowbase + C_DIM + col]     = f2bf(ya[nb][1] * lA1);
    Y[rowbase + 2 * C_DIM + col] = f2bf(ya[nb][2] * lA2);
    Y[rowbase + 3 * C_DIM + col] = f2bf(ya[nb][3] * lA3);
  }
  float liB = 1.f / lB;
  float lB0 = __shfl(liB, 4 * g + 0);
  float lB1 = __shfl(liB, 4 * g + 1);
  float lB2 = __shfl(liB, 4 * g + 2);
  float lB3 = __shfl(liB, 4 * g + 3);
  rowbase += (size_t)16 * C_DIM;
#pragma unroll
  for (int nb = 0; nb < 4; ++nb) {
    int col = hh * 64 + nb * 16 + i;
    Y[rowbase + col]             = f2bf(yb[nb][0] * lB0);
    Y[rowbase + C_DIM + col]     = f2bf(yb[nb][1] * lB1);
    Y[rowbase + 2 * C_DIM + col] = f2bf(yb[nb][2] * lB2);
    Y[rowbase + 3 * C_DIM + col] = f2bf(yb[nb][3] * lB3);
  }
}

extern "C" void kernel_launch(void* const* d_in, const int* in_sizes, int n_in,
                              void* d_out, int out_size, void* d_ws, size_t ws_size,
                              hipStream_t stream) {
  const float* x      = (const float*)d_in[0];
  const float* W_attn = (const float*)d_in[1];
  const float* b_attn = (const float*)d_in[2];
  const float* W_proj = (const float*)d_in[3];
  const float* b_proj = (const float*)d_in[4];
  float* out = (float*)d_out;

  unsigned short* Wkt  = (unsigned short*)d_ws;                 // 1024x1024 bf16
  unsigned short* Wpt  = Wkt + (size_t)1024 * 1024;             // 1024x1024 bf16
  unsigned short* Khb  = Wpt + (size_t)1024 * 1024;             // [64][2048][64] bf16
  unsigned short* Ybuf = Khb + (size_t)8192 * 1024;             // 8192x1024 bf16
  unsigned short* Vtb  = Ybuf + (size_t)8192 * 1024;            // [64][64][2048] bf16

  transpose_w<<<dim3(64, 64), dim3(16, 16), 0, stream>>>(W_attn, Wkt, 3072, 1024);
  transpose_w<<<dim3(64, 64), dim3(16, 16), 0, stream>>>(W_proj, Wpt, 1024, 0);

  // K (head-blocked) + V^T = x @ Wk + b_attn[C:2C]
  gemm_xw<<<dim3(64, 8), 256, 0, stream>>>(x, Wkt, b_attn + 1024, Khb, Vtb);

  // y = causal_attn(K,K,K), 1 wave/block, descending-work order + HW backfill
  attn_fwd<<<dim3(4096), 64, 0, stream>>>(Khb, Vtb, Ybuf);

  // out = y @ Wp + b_proj
  gemm_yw<<<dim3(64, 8), 256, 0, stream>>>(Ybuf, Wpt, b_proj, out);
}